// Round 1
// baseline (5851.285 us; speedup 1.0000x reference)
//
#include <hip/hip_runtime.h>

#define N_NODES 65536
#define N_EDGES 1048576
#define N_LABEL 2097152
#define DIM_IN 32
#define DIM_H 64

// ---------------- degree / norm precompute ----------------

__global__ void k_deg_init(float* __restrict__ deg) {
    int v = blockIdx.x * blockDim.x + threadIdx.x;
    deg[v] = 1.0f;  // self-loop weight
}

__global__ void k_deg_scatter(const int* __restrict__ ei, const float* __restrict__ w,
                              float* __restrict__ deg) {
    int e = blockIdx.x * blockDim.x + threadIdx.x;
    atomicAdd(&deg[ei[N_EDGES + e]], w[e]);
}

__global__ void k_dinv(float* __restrict__ deg) {
    int v = blockIdx.x * blockDim.x + threadIdx.x;
    deg[v] = rsqrtf(deg[v]);  // deg >= 1 always (self-loop)
}

__global__ void k_norm(const int* __restrict__ ei, const float* __restrict__ w,
                       const float* __restrict__ dinv, float* __restrict__ nrm) {
    int e = blockIdx.x * blockDim.x + threadIdx.x;
    nrm[e] = dinv[ei[e]] * w[e] * dinv[ei[N_EDGES + e]];
}

// ---------------- dense transform: t = h @ W  (h: N x K, W: K x 64) ----------------

template <int K>
__global__ void k_gemm(const float* __restrict__ h, const float* __restrict__ W,
                       float* __restrict__ t) {
    __shared__ float Wl[K * 64];
    int tid = threadIdx.x;
    for (int i = tid; i < K * 64; i += 256) Wl[i] = W[i];
    __syncthreads();
    int row = blockIdx.x * 4 + (tid >> 6);
    int col = tid & 63;
    const float* hr = h + (size_t)row * K;
    float acc = 0.0f;
#pragma unroll
    for (int k = 0; k < K; ++k) acc += hr[k] * Wl[k * 64 + col];
    t[(size_t)row * 64 + col] = acc;
}

// ---------------- aggregation ----------------

// agg[v] = dinv[v]^2 * t[v]  (self-loop term; also serves as zero-init)
__global__ void k_scatter_init(const float4* __restrict__ t4, const float* __restrict__ dinv,
                               float4* __restrict__ agg4) {
    int gid = blockIdx.x * blockDim.x + threadIdx.x;  // N*16 threads
    int v = gid >> 4;
    float d = dinv[v];
    float s = d * d;
    float4 tv = t4[gid];
    agg4[gid] = make_float4(s * tv.x, s * tv.y, s * tv.z, s * tv.w);
}

// agg[dst] += norm[e] * t[src] ; 16 threads per edge, float4 each
__global__ void k_scatter_edges(const int* __restrict__ ei, const float* __restrict__ nrm,
                                const float4* __restrict__ t4, float* __restrict__ agg) {
    int gid = blockIdx.x * blockDim.x + threadIdx.x;  // E*16 threads
    int e = gid >> 4;
    int c4 = gid & 15;
    int s = ei[e];
    int d = ei[N_EDGES + e];
    float nm = nrm[e];
    float4 tv = t4[(size_t)s * 16 + c4];
    float* out = agg + (size_t)d * 64 + c4 * 4;
    atomicAdd(out + 0, nm * tv.x);
    atomicAdd(out + 1, nm * tv.y);
    atomicAdd(out + 2, nm * tv.z);
    atomicAdd(out + 3, nm * tv.w);
}

// in-place: agg = (agg + b)  [+ relu]
template <bool RELU>
__global__ void k_bias(float4* __restrict__ agg4, const float* __restrict__ b) {
    int gid = blockIdx.x * blockDim.x + threadIdx.x;  // N*16 threads
    int c4 = gid & 15;
    const float4 bv = *reinterpret_cast<const float4*>(b + c4 * 4);
    float4 a = agg4[gid];
    a.x += bv.x; a.y += bv.y; a.z += bv.z; a.w += bv.w;
    if (RELU) {
        a.x = fmaxf(a.x, 0.0f); a.y = fmaxf(a.y, 0.0f);
        a.z = fmaxf(a.z, 0.0f); a.w = fmaxf(a.w, 0.0f);
    }
    agg4[gid] = a;
}

// ---------------- decode: out[p] = dot(enc[a], enc[b]) ----------------

__global__ void k_decode(const int* __restrict__ eli, const float4* __restrict__ enc4,
                         float* __restrict__ out) {
    int gid = blockIdx.x * blockDim.x + threadIdx.x;  // EL*16 threads
    int p = gid >> 4;
    int c4 = gid & 15;
    int a = eli[p];
    int b = eli[N_LABEL + p];
    float4 ea = enc4[(size_t)a * 16 + c4];
    float4 eb = enc4[(size_t)b * 16 + c4];
    float s = ea.x * eb.x + ea.y * eb.y + ea.z * eb.z + ea.w * eb.w;
#pragma unroll
    for (int m = 8; m >= 1; m >>= 1) s += __shfl_xor(s, m, 16);
    if (c4 == 0) out[p] = s;
}

// ---------------- host ----------------

extern "C" void kernel_launch(void* const* d_in, const int* in_sizes, int n_in,
                              void* d_out, int out_size, void* d_ws, size_t ws_size,
                              hipStream_t stream) {
    const float* x   = (const float*)d_in[0];
    const int*   ei  = (const int*)d_in[1];
    const float* ew  = (const float*)d_in[2];
    const int*   eli = (const int*)d_in[3];
    const float* W[6] = {(const float*)d_in[4],  (const float*)d_in[6],
                         (const float*)d_in[8],  (const float*)d_in[10],
                         (const float*)d_in[12], (const float*)d_in[14]};
    const float* B[6] = {(const float*)d_in[5],  (const float*)d_in[7],
                         (const float*)d_in[9],  (const float*)d_in[11],
                         (const float*)d_in[13], (const float*)d_in[15]};

    float* ws   = (float*)d_ws;
    float* dinv = ws;                          // N floats (deg, then in-place rsqrt)
    float* nrm  = dinv + N_NODES;              // E floats
    float* bufH = nrm + N_EDGES;               // N*64 floats (agg / h)
    float* bufT = bufH + (size_t)N_NODES * 64; // N*64 floats (t)

    const int BS = 256;

    // norm precompute
    k_deg_init<<<N_NODES / BS, BS, 0, stream>>>(dinv);
    k_deg_scatter<<<N_EDGES / BS, BS, 0, stream>>>(ei, ew, dinv);
    k_dinv<<<N_NODES / BS, BS, 0, stream>>>(dinv);
    k_norm<<<N_EDGES / BS, BS, 0, stream>>>(ei, ew, dinv, nrm);

    const int gNode4 = N_NODES * 16 / BS;   // float4-per-thread node kernels
    const int gEdge  = N_EDGES * 16 / BS;

    // layer 1 (K = 32, input = x)
    k_gemm<DIM_IN><<<N_NODES / 4, BS, 0, stream>>>(x, W[0], bufT);
    k_scatter_init<<<gNode4, BS, 0, stream>>>((const float4*)bufT, dinv, (float4*)bufH);
    k_scatter_edges<<<gEdge, BS, 0, stream>>>(ei, nrm, (const float4*)bufT, bufH);
    k_bias<true><<<gNode4, BS, 0, stream>>>((float4*)bufH, B[0]);

    // layers 2..5 (K = 64, relu)
    for (int l = 1; l < 5; ++l) {
        k_gemm<DIM_H><<<N_NODES / 4, BS, 0, stream>>>(bufH, W[l], bufT);
        k_scatter_init<<<gNode4, BS, 0, stream>>>((const float4*)bufT, dinv, (float4*)bufH);
        k_scatter_edges<<<gEdge, BS, 0, stream>>>(ei, nrm, (const float4*)bufT, bufH);
        k_bias<true><<<gNode4, BS, 0, stream>>>((float4*)bufH, B[l]);
    }

    // layer 6 (no relu)
    k_gemm<DIM_H><<<N_NODES / 4, BS, 0, stream>>>(bufH, W[5], bufT);
    k_scatter_init<<<gNode4, BS, 0, stream>>>((const float4*)bufT, dinv, (float4*)bufH);
    k_scatter_edges<<<gEdge, BS, 0, stream>>>(ei, nrm, (const float4*)bufT, bufH);
    k_bias<false><<<gNode4, BS, 0, stream>>>((float4*)bufH, B[5]);

    // decode
    k_decode<<<N_LABEL * 16 / BS, BS, 0, stream>>>(eli, (const float4*)bufH, (float*)d_out);
}

// Round 2
// 966.127 us; speedup vs baseline: 6.0564x; 6.0564x over previous
//
#include <hip/hip_runtime.h>

#define N_NODES 65536
#define N_EDGES 1048576
#define N_LABEL 2097152
#define DIM_IN 32
#define DIM_H 64

// ---------------- CSR build + norm precompute ----------------

__global__ void k_init(float* __restrict__ deg, int* __restrict__ cnt) {
    int v = blockIdx.x * blockDim.x + threadIdx.x;
    deg[v] = 1.0f;  // self-loop weight
    cnt[v] = 0;
}

__global__ void k_cnt(const int* __restrict__ ei, const float* __restrict__ w,
                      int* __restrict__ cnt, float* __restrict__ deg) {
    int e = blockIdx.x * blockDim.x + threadIdx.x;
    int d = ei[N_EDGES + e];
    atomicAdd(&cnt[d], 1);
    atomicAdd(&deg[d], w[e]);
}

// single-block exclusive scan over 65536 counts -> offs[N+1], cursor[N]
__global__ void k_scan(const int* __restrict__ cnt, int* __restrict__ offs,
                       int* __restrict__ cursor) {
    __shared__ int sums[257];
    int tid = threadIdx.x;
    int base = tid * 256;
    int s = 0;
    for (int i = 0; i < 256; ++i) s += cnt[base + i];
    sums[tid] = s;
    __syncthreads();
    if (tid == 0) {
        int run = 0;
        for (int i = 0; i < 256; ++i) { int t = sums[i]; sums[i] = run; run += t; }
    }
    __syncthreads();
    int run = sums[tid];
    for (int i = 0; i < 256; ++i) {
        offs[base + i] = run;
        cursor[base + i] = run;
        run += cnt[base + i];
    }
    if (tid == 255) offs[N_NODES] = run;
}

__global__ void k_dinv(float* __restrict__ deg) {
    int v = blockIdx.x * blockDim.x + threadIdx.x;
    deg[v] = rsqrtf(deg[v]);  // deg >= 1 always (self-loop)
}

__global__ void k_fill(const int* __restrict__ ei, const float* __restrict__ w,
                       const float* __restrict__ dinv, int* __restrict__ cursor,
                       int* __restrict__ csr_src, float* __restrict__ csr_nrm) {
    int e = blockIdx.x * blockDim.x + threadIdx.x;
    int s = ei[e];
    int d = ei[N_EDGES + e];
    int pos = atomicAdd(&cursor[d], 1);
    csr_src[pos] = s;
    csr_nrm[pos] = dinv[s] * w[e] * dinv[d];
}

// ---------------- dense transform: t = h @ W  (h: N x K, W: K x 64) ----------------

template <int K>
__global__ void k_gemm(const float* __restrict__ h, const float* __restrict__ W,
                       float* __restrict__ t) {
    __shared__ float Wl[K * 64];
    int tid = threadIdx.x;
    for (int i = tid; i < K * 64; i += 256) Wl[i] = W[i];
    __syncthreads();
    int row = blockIdx.x * 4 + (tid >> 6);
    int col = tid & 63;
    const float* hr = h + (size_t)row * K;
    float acc = 0.0f;
#pragma unroll
    for (int k = 0; k < K; ++k) acc += hr[k] * Wl[k * 64 + col];
    t[(size_t)row * 64 + col] = acc;
}

// ---------------- gather aggregation: out[v] = relu(dinv[v]^2*t[v] + sum_in + b) ----------------

template <bool RELU>
__global__ void k_aggregate(const int* __restrict__ offs, const int* __restrict__ csr_src,
                            const float* __restrict__ csr_nrm, const float4* __restrict__ t4,
                            const float* __restrict__ dinv, const float* __restrict__ b,
                            float4* __restrict__ out4) {
    int tid = threadIdx.x;
    int v = blockIdx.x * 16 + (tid >> 4);  // 16 lanes per node
    int c4 = tid & 15;
    float dv = dinv[v];
    float sl = dv * dv;
    float4 acc = t4[v * 16 + c4];
    acc.x *= sl; acc.y *= sl; acc.z *= sl; acc.w *= sl;
    int j1 = offs[v + 1];
    for (int j = offs[v]; j < j1; ++j) {
        int s = csr_src[j];        // broadcast across the 16 lanes
        float nm = csr_nrm[j];
        float4 tv = t4[s * 16 + c4];
        acc.x += nm * tv.x; acc.y += nm * tv.y;
        acc.z += nm * tv.z; acc.w += nm * tv.w;
    }
    const float4 bv = *reinterpret_cast<const float4*>(b + c4 * 4);
    acc.x += bv.x; acc.y += bv.y; acc.z += bv.z; acc.w += bv.w;
    if (RELU) {
        acc.x = fmaxf(acc.x, 0.0f); acc.y = fmaxf(acc.y, 0.0f);
        acc.z = fmaxf(acc.z, 0.0f); acc.w = fmaxf(acc.w, 0.0f);
    }
    out4[v * 16 + c4] = acc;
}

// ---------------- decode: out[p] = dot(enc[a], enc[b]) ----------------

__global__ void k_decode(const int* __restrict__ eli, const float4* __restrict__ enc4,
                         float* __restrict__ out) {
    int gid = blockIdx.x * blockDim.x + threadIdx.x;  // EL*16 threads
    int p = gid >> 4;
    int c4 = gid & 15;
    int a = eli[p];
    int b = eli[N_LABEL + p];
    float4 ea = enc4[(size_t)a * 16 + c4];
    float4 eb = enc4[(size_t)b * 16 + c4];
    float s = ea.x * eb.x + ea.y * eb.y + ea.z * eb.z + ea.w * eb.w;
#pragma unroll
    for (int m = 8; m >= 1; m >>= 1) s += __shfl_xor(s, m, 16);
    if (c4 == 0) out[p] = s;
}

// ---------------- host ----------------

extern "C" void kernel_launch(void* const* d_in, const int* in_sizes, int n_in,
                              void* d_out, int out_size, void* d_ws, size_t ws_size,
                              hipStream_t stream) {
    const float* x   = (const float*)d_in[0];
    const int*   ei  = (const int*)d_in[1];
    const float* ew  = (const float*)d_in[2];
    const int*   eli = (const int*)d_in[3];
    const float* W[6] = {(const float*)d_in[4],  (const float*)d_in[6],
                         (const float*)d_in[8],  (const float*)d_in[10],
                         (const float*)d_in[12], (const float*)d_in[14]};
    const float* B[6] = {(const float*)d_in[5],  (const float*)d_in[7],
                         (const float*)d_in[9],  (const float*)d_in[11],
                         (const float*)d_in[13], (const float*)d_in[15]};

    char* ws = (char*)d_ws;
    float* dinv    = (float*)ws;                 ws += N_NODES * 4;        // deg -> rsqrt in place
    int*   cnt     = (int*)ws;                   ws += N_NODES * 4;
    int*   offs    = (int*)ws;                   ws += (N_NODES + 16) * 4;
    int*   cursor  = (int*)ws;                   ws += N_NODES * 4;
    int*   csr_src = (int*)ws;                   ws += N_EDGES * 4;
    float* csr_nrm = (float*)ws;                 ws += N_EDGES * 4;
    float* bufH    = (float*)ws;                 ws += (size_t)N_NODES * 64 * 4;
    float* bufT    = (float*)ws;

    const int BS = 256;
    const int gN = N_NODES / BS;
    const int gE = N_EDGES / BS;
    const int gNode16 = N_NODES * 16 / BS;  // 16 lanes per node

    // CSR build + norm
    k_init<<<gN, BS, 0, stream>>>(dinv, cnt);
    k_cnt<<<gE, BS, 0, stream>>>(ei, ew, cnt, dinv);
    k_scan<<<1, 256, 0, stream>>>(cnt, offs, cursor);
    k_dinv<<<gN, BS, 0, stream>>>(dinv);
    k_fill<<<gE, BS, 0, stream>>>(ei, ew, dinv, cursor, csr_src, csr_nrm);

    // layer 1 (K = 32, input = x)
    k_gemm<DIM_IN><<<N_NODES / 4, BS, 0, stream>>>(x, W[0], bufT);
    k_aggregate<true><<<gNode16, BS, 0, stream>>>(offs, csr_src, csr_nrm,
                                                  (const float4*)bufT, dinv, B[0], (float4*)bufH);

    // layers 2..5 (K = 64, relu)
    for (int l = 1; l < 5; ++l) {
        k_gemm<DIM_H><<<N_NODES / 4, BS, 0, stream>>>(bufH, W[l], bufT);
        k_aggregate<true><<<gNode16, BS, 0, stream>>>(offs, csr_src, csr_nrm,
                                                      (const float4*)bufT, dinv, B[l], (float4*)bufH);
    }

    // layer 6 (no relu)
    k_gemm<DIM_H><<<N_NODES / 4, BS, 0, stream>>>(bufH, W[5], bufT);
    k_aggregate<false><<<gNode16, BS, 0, stream>>>(offs, csr_src, csr_nrm,
                                                   (const float4*)bufT, dinv, B[5], (float4*)bufH);

    // decode
    k_decode<<<N_LABEL * 16 / BS, BS, 0, stream>>>(eli, (const float4*)bufH, (float*)d_out);
}

// Round 3
// 894.567 us; speedup vs baseline: 6.5409x; 1.0800x over previous
//
#include <hip/hip_runtime.h>

#define N_NODES 65536
#define N_EDGES 1048576
#define N_LABEL 2097152
#define DIM_IN 32
#define DIM_H 64

// ---------------- CSR build + norm precompute ----------------

__global__ void k_init(float* __restrict__ deg, int* __restrict__ cnt) {
    int v = blockIdx.x * blockDim.x + threadIdx.x;
    deg[v] = 1.0f;  // self-loop weight
    cnt[v] = 0;
}

__global__ void k_cnt(const int* __restrict__ ei, const float* __restrict__ w,
                      int* __restrict__ cnt, float* __restrict__ deg) {
    int e = blockIdx.x * blockDim.x + threadIdx.x;
    int d = ei[N_EDGES + e];
    atomicAdd(&cnt[d], 1);
    atomicAdd(&deg[d], w[e]);
}

// single-block exclusive scan over 65536 counts -> offs[N+1], cursor[N]
__global__ void k_scan(const int* __restrict__ cnt, int* __restrict__ offs,
                       int* __restrict__ cursor) {
    __shared__ int sums[257];
    int tid = threadIdx.x;
    int base = tid * 256;
    int s = 0;
    for (int i = 0; i < 256; ++i) s += cnt[base + i];
    sums[tid] = s;
    __syncthreads();
    if (tid == 0) {
        int run = 0;
        for (int i = 0; i < 256; ++i) { int t = sums[i]; sums[i] = run; run += t; }
    }
    __syncthreads();
    int run = sums[tid];
    for (int i = 0; i < 256; ++i) {
        offs[base + i] = run;
        cursor[base + i] = run;
        run += cnt[base + i];
    }
    if (tid == 255) offs[N_NODES] = run;
}

__global__ void k_dinv(float* __restrict__ deg) {
    int v = blockIdx.x * blockDim.x + threadIdx.x;
    deg[v] = rsqrtf(deg[v]);  // deg >= 1 always (self-loop)
}

__global__ void k_fill(const int* __restrict__ ei, const float* __restrict__ w,
                       const float* __restrict__ dinv, int* __restrict__ cursor,
                       int* __restrict__ csr_src, float* __restrict__ csr_nrm) {
    int e = blockIdx.x * blockDim.x + threadIdx.x;
    int s = ei[e];
    int d = ei[N_EDGES + e];
    int pos = atomicAdd(&cursor[d], 1);
    csr_src[pos] = s;
    csr_nrm[pos] = dinv[s] * w[e] * dinv[d];
}

// ---------------- fused layer: out[v] = relu( (Ah)[v] @ W + b ) ----------------
// One 64-lane wave per node. Lane = input dim (mod K) during gather,
// lane = output col during transform.

template <int K, bool RELU>
__global__ void __launch_bounds__(256) k_layer(
        const int* __restrict__ offs, const int* __restrict__ csr_src,
        const float* __restrict__ csr_nrm, const float* __restrict__ h,
        const float* __restrict__ dinv, const float* __restrict__ W,
        const float* __restrict__ b, float* __restrict__ out) {
    __shared__ float Wl[K * 64];
    int tid = threadIdx.x;
    for (int i = tid; i < K * 64; i += 256) Wl[i] = W[i];
    __syncthreads();

    int v = blockIdx.x * 4 + (tid >> 6);
    int lane = tid & 63;
    int k = lane & (K - 1);

    float dv = dinv[v];
    float acc = dv * dv * h[(size_t)v * K + k];  // self-loop term

    int j0 = __builtin_amdgcn_readfirstlane(offs[v]);
    int j1 = __builtin_amdgcn_readfirstlane(offs[v + 1]);
    int j = j0;
    for (; j + 8 <= j1; j += 8) {
        int s0 = __builtin_amdgcn_readfirstlane(csr_src[j + 0]);
        int s1 = __builtin_amdgcn_readfirstlane(csr_src[j + 1]);
        int s2 = __builtin_amdgcn_readfirstlane(csr_src[j + 2]);
        int s3 = __builtin_amdgcn_readfirstlane(csr_src[j + 3]);
        int s4 = __builtin_amdgcn_readfirstlane(csr_src[j + 4]);
        int s5 = __builtin_amdgcn_readfirstlane(csr_src[j + 5]);
        int s6 = __builtin_amdgcn_readfirstlane(csr_src[j + 6]);
        int s7 = __builtin_amdgcn_readfirstlane(csr_src[j + 7]);
        float n0 = csr_nrm[j + 0], n1 = csr_nrm[j + 1];
        float n2 = csr_nrm[j + 2], n3 = csr_nrm[j + 3];
        float n4 = csr_nrm[j + 4], n5 = csr_nrm[j + 5];
        float n6 = csr_nrm[j + 6], n7 = csr_nrm[j + 7];
        float r0 = h[(size_t)s0 * K + k];
        float r1 = h[(size_t)s1 * K + k];
        float r2 = h[(size_t)s2 * K + k];
        float r3 = h[(size_t)s3 * K + k];
        float r4 = h[(size_t)s4 * K + k];
        float r5 = h[(size_t)s5 * K + k];
        float r6 = h[(size_t)s6 * K + k];
        float r7 = h[(size_t)s7 * K + k];
        acc += n0 * r0; acc += n1 * r1; acc += n2 * r2; acc += n3 * r3;
        acc += n4 * r4; acc += n5 * r5; acc += n6 * r6; acc += n7 * r7;
    }
    for (; j < j1; ++j) {
        int s = __builtin_amdgcn_readfirstlane(csr_src[j]);
        float nm = csr_nrm[j];
        acc += nm * h[(size_t)s * K + k];
    }

    // transform: o[lane] = sum_k acc[k] * W[k][lane]
    float o0 = 0.f, o1 = 0.f, o2 = 0.f, o3 = 0.f;
#pragma unroll
    for (int kk = 0; kk < K; kk += 4) {
        o0 += __shfl(acc, kk + 0) * Wl[(kk + 0) * 64 + lane];
        o1 += __shfl(acc, kk + 1) * Wl[(kk + 1) * 64 + lane];
        o2 += __shfl(acc, kk + 2) * Wl[(kk + 2) * 64 + lane];
        o3 += __shfl(acc, kk + 3) * Wl[(kk + 3) * 64 + lane];
    }
    float o = (o0 + o1) + (o2 + o3) + b[lane];
    if (RELU) o = fmaxf(o, 0.f);
    out[(size_t)v * 64 + lane] = o;
}

// ---------------- decode: out[p] = dot(enc[a], enc[b]) ----------------

__global__ void k_decode(const int* __restrict__ eli, const float4* __restrict__ enc4,
                         float* __restrict__ out) {
    int gid = blockIdx.x * blockDim.x + threadIdx.x;  // EL*16 threads
    int p = gid >> 4;
    int c4 = gid & 15;
    int a = eli[p];
    int b = eli[N_LABEL + p];
    float4 ea = enc4[(size_t)a * 16 + c4];
    float4 eb = enc4[(size_t)b * 16 + c4];
    float s = ea.x * eb.x + ea.y * eb.y + ea.z * eb.z + ea.w * eb.w;
#pragma unroll
    for (int m = 8; m >= 1; m >>= 1) s += __shfl_xor(s, m, 16);
    if (c4 == 0) out[p] = s;
}

// ---------------- host ----------------

extern "C" void kernel_launch(void* const* d_in, const int* in_sizes, int n_in,
                              void* d_out, int out_size, void* d_ws, size_t ws_size,
                              hipStream_t stream) {
    const float* x   = (const float*)d_in[0];
    const int*   ei  = (const int*)d_in[1];
    const float* ew  = (const float*)d_in[2];
    const int*   eli = (const int*)d_in[3];
    const float* W[6] = {(const float*)d_in[4],  (const float*)d_in[6],
                         (const float*)d_in[8],  (const float*)d_in[10],
                         (const float*)d_in[12], (const float*)d_in[14]};
    const float* B[6] = {(const float*)d_in[5],  (const float*)d_in[7],
                         (const float*)d_in[9],  (const float*)d_in[11],
                         (const float*)d_in[13], (const float*)d_in[15]};

    char* ws = (char*)d_ws;
    float* dinv    = (float*)ws;                 ws += N_NODES * 4;        // deg -> rsqrt in place
    int*   cnt     = (int*)ws;                   ws += N_NODES * 4;
    int*   offs    = (int*)ws;                   ws += (N_NODES + 16) * 4;
    int*   cursor  = (int*)ws;                   ws += N_NODES * 4;
    int*   csr_src = (int*)ws;                   ws += N_EDGES * 4;
    float* csr_nrm = (float*)ws;                 ws += N_EDGES * 4;
    float* bufA    = (float*)ws;                 ws += (size_t)N_NODES * 64 * 4;
    float* bufB    = (float*)ws;

    const int BS = 256;
    const int gN = N_NODES / BS;
    const int gE = N_EDGES / BS;
    const int gLayer = N_NODES / 4;  // one 64-lane wave per node, 4 per block

    // CSR build + norm
    k_init<<<gN, BS, 0, stream>>>(dinv, cnt);
    k_cnt<<<gE, BS, 0, stream>>>(ei, ew, cnt, dinv);
    k_scan<<<1, 256, 0, stream>>>(cnt, offs, cursor);
    k_dinv<<<gN, BS, 0, stream>>>(dinv);
    k_fill<<<gE, BS, 0, stream>>>(ei, ew, dinv, cursor, csr_src, csr_nrm);

    // fused layers
    k_layer<DIM_IN, true><<<gLayer, BS, 0, stream>>>(offs, csr_src, csr_nrm, x,    dinv, W[0], B[0], bufA);
    k_layer<DIM_H,  true><<<gLayer, BS, 0, stream>>>(offs, csr_src, csr_nrm, bufA, dinv, W[1], B[1], bufB);
    k_layer<DIM_H,  true><<<gLayer, BS, 0, stream>>>(offs, csr_src, csr_nrm, bufB, dinv, W[2], B[2], bufA);
    k_layer<DIM_H,  true><<<gLayer, BS, 0, stream>>>(offs, csr_src, csr_nrm, bufA, dinv, W[3], B[3], bufB);
    k_layer<DIM_H,  true><<<gLayer, BS, 0, stream>>>(offs, csr_src, csr_nrm, bufB, dinv, W[4], B[4], bufA);
    k_layer<DIM_H, false><<<gLayer, BS, 0, stream>>>(offs, csr_src, csr_nrm, bufA, dinv, W[5], B[5], bufB);

    // decode
    k_decode<<<N_LABEL * 16 / BS, BS, 0, stream>>>(eli, (const float4*)bufB, (float*)d_out);
}